// Round 5
// baseline (1363.638 us; speedup 1.0000x reference)
//
#include <hip/hip_runtime.h>
#include <math.h>

#define B_SZ 2
#define S_LEN 2048
#define HID_D 4096
#define NH 32
#define NKV 8
#define HD 128
#define NTOK (B_SZ * S_LEN)

typedef short bf16x8 __attribute__((ext_vector_type(8)));
typedef float f32x4 __attribute__((ext_vector_type(4)));

__device__ inline unsigned short bf_rn(float f) {
    unsigned int u = __builtin_bit_cast(unsigned int, f);
    return (unsigned short)((u + 0x7FFFu + ((u >> 16) & 1u)) >> 16);
}
__device__ inline float bf_up(unsigned short s) {
    return __builtin_bit_cast(float, (unsigned int)s << 16);
}

__device__ inline void gload_lds16(const void* g, void* l) {
    __builtin_amdgcn_global_load_lds(
        (const __attribute__((address_space(1))) unsigned int*)g,
        (__attribute__((address_space(3))) unsigned int*)l, 16, 0, 0);
}

// ---------------------------------------------------------------------------
// cos/sin table: [S][64], from positions (int32).
// ---------------------------------------------------------------------------
__global__ __launch_bounds__(64) void rope_table_kernel(const int* __restrict__ pos,
                                                        float* __restrict__ cosT,
                                                        float* __restrict__ sinT) {
    int s = blockIdx.x;
    int i = threadIdx.x;
    float p = (float)pos[s];
    float inv = expf((float)i * (-13.815510557964274f / 64.0f));
    float f = p * inv;
    cosT[s * 64 + i] = cosf(f);
    sinT[s * 64 + i] = sinf(f);
}

// ---------------------------------------------------------------------------
// fp32 -> bf16 cast, vectorized.
// ---------------------------------------------------------------------------
__global__ __launch_bounds__(256) void castv_kernel(const float* __restrict__ src,
                                                    unsigned short* __restrict__ dst,
                                                    int nquads) {
    int i = blockIdx.x * 256 + threadIdx.x;
    if (i >= nquads) return;
    float4 v = ((const float4*)src)[i];
    ushort4 o;
    o.x = bf_rn(v.x); o.y = bf_rn(v.y); o.z = bf_rn(v.z); o.w = bf_rn(v.w);
    ((ushort4*)dst)[i] = o;
}

// ---------------------------------------------------------------------------
// fused cast + transpose: src[K][N] f32 -> dst[N][K] bf16. 32x32 LDS tile.
// ---------------------------------------------------------------------------
__global__ __launch_bounds__(256) void cast_t_kernel(const float* __restrict__ src,
                                                     unsigned short* __restrict__ dst,
                                                     int K, int N) {
    __shared__ float tile[32][33];
    const int j0 = blockIdx.x << 5;
    const int i0 = blockIdx.y << 5;
    const int tx = threadIdx.x & 31, ty = threadIdx.x >> 5;
#pragma unroll
    for (int r = 0; r < 32; r += 8)
        tile[ty + r][tx] = src[(size_t)(i0 + ty + r) * N + j0 + tx];
    __syncthreads();
#pragma unroll
    for (int r = 0; r < 32; r += 8)
        dst[(size_t)(j0 + ty + r) * K + i0 + tx] = bf_rn(tile[tx][ty + r]);
}

// ---------------------------------------------------------------------------
// V transpose: vout [B][S][KVH][HD] f32 -> vtb [B][KVH][HD][S] bf16.
// Per-(b,kvh) 2048x128 -> 128x2048 transpose, 32x32 LDS tiles.
// ---------------------------------------------------------------------------
__global__ __launch_bounds__(256) void vtrans_kernel(const float* __restrict__ vout,
                                                     unsigned short* __restrict__ vtb) {
    __shared__ float tile[32][33];
    const int bh = blockIdx.z;           // b*NKV + kvh
    const int s0 = blockIdx.x << 5;
    const int d0 = blockIdx.y << 5;
    const int b = bh >> 3, kvh = bh & 7;
    const int tx = threadIdx.x & 31, ty = threadIdx.x >> 5;
#pragma unroll
    for (int r = 0; r < 32; r += 8)
        tile[ty + r][tx] = vout[((size_t)(b * S_LEN + s0 + ty + r) * NKV + kvh) * HD + d0 + tx];
    __syncthreads();
#pragma unroll
    for (int r = 0; r < 32; r += 8)
        vtb[((size_t)(b * NKV + kvh) * HD + d0 + ty + r) * S_LEN + s0 + tx] = bf_rn(tile[tx][ty + r]);
}

// ---------------------------------------------------------------------------
// bf16 MFMA GEMM (m97 structure): C[M][N] = sum_k A[m][k] * Bt[n][k].
// 128x128 tile, BK=32, 4 waves, 16x16x32, global_load_lds width-16 staging.
// OUT = float (direct) or unsigned short (bf16 epilogue cast).
// ---------------------------------------------------------------------------
template <typename OUT>
__global__ __launch_bounds__(256) void gemm_bt_kernel(const unsigned short* __restrict__ A,
                                                      const unsigned short* __restrict__ Bt,
                                                      OUT* __restrict__ C,
                                                      int M, int N, int K) {
    __shared__ unsigned short As[128 * 32];
    __shared__ unsigned short Bs[128 * 32];
    const int t = threadIdx.x;
    const int lane = t & 63, w = t >> 6;
    const int wr = w >> 1, wc = w & 1;
    const int bm = blockIdx.y << 7, bn = blockIdx.x << 7;

    const int srow = w * 32 + (lane >> 2);
    const int skoff = (lane & 3) << 3;
    const unsigned short* aA0 = A + (size_t)(bm + srow) * K + skoff;
    const unsigned short* aA1 = aA0 + (size_t)16 * K;
    const unsigned short* aB0 = Bt + (size_t)(bn + srow) * K + skoff;
    const unsigned short* aB1 = aB0 + (size_t)16 * K;
    unsigned short* lA0 = As + (w * 2 + 0) * 512;
    unsigned short* lA1 = As + (w * 2 + 1) * 512;
    unsigned short* lB0 = Bs + (w * 2 + 0) * 512;
    unsigned short* lB1 = Bs + (w * 2 + 1) * 512;

    const int fr = lane & 15, fg = lane >> 4;
    const unsigned short* Asp = As + (wr * 64 + fr) * 32 + fg * 8;
    const unsigned short* Bsp = Bs + (wc * 64 + fr) * 32 + fg * 8;

    f32x4 acc[4][4];
#pragma unroll
    for (int m = 0; m < 4; ++m)
#pragma unroll
        for (int n = 0; n < 4; ++n) acc[m][n] = (f32x4)(0.0f);

    const int nk = K >> 5;
    for (int kc = 0; kc < nk; ++kc) {
        __syncthreads();
        const size_t go = (size_t)kc * 32;
        gload_lds16(aA0 + go, lA0);
        gload_lds16(aA1 + go, lA1);
        gload_lds16(aB0 + go, lB0);
        gload_lds16(aB1 + go, lB1);
        __syncthreads();

        bf16x8 af[4], bfr[4];
#pragma unroll
        for (int m = 0; m < 4; ++m) af[m] = *(const bf16x8*)(Asp + m * 512);
#pragma unroll
        for (int n = 0; n < 4; ++n) bfr[n] = *(const bf16x8*)(Bsp + n * 512);
#pragma unroll
        for (int m = 0; m < 4; ++m)
#pragma unroll
            for (int n = 0; n < 4; ++n)
                acc[m][n] = __builtin_amdgcn_mfma_f32_16x16x32_bf16(af[m], bfr[n], acc[m][n], 0, 0, 0);
    }

    const int crow = (lane >> 4) << 2, ccol = lane & 15;
#pragma unroll
    for (int m = 0; m < 4; ++m)
#pragma unroll
        for (int n = 0; n < 4; ++n) {
            OUT* Cp = C + (size_t)(bm + wr * 64 + m * 16 + crow) * N + bn + wc * 64 + n * 16 + ccol;
#pragma unroll
            for (int r = 0; r < 4; ++r) {
                float v = acc[m][n][r];
                if constexpr (sizeof(OUT) == 2) Cp[(size_t)r * N] = bf_rn(v);
                else                            Cp[(size_t)r * N] = v;
            }
        }
}

// ---------------------------------------------------------------------------
// In-place RMSNorm(+weight) + interleaved RoPE, f32 buffer (k path).
// ---------------------------------------------------------------------------
__global__ __launch_bounds__(64) void norm_rope_kernel(float* __restrict__ buf,
                                                       const float* __restrict__ w,
                                                       const float* __restrict__ cosT,
                                                       const float* __restrict__ sinT,
                                                       int nh) {
    int bid = blockIdx.x;
    int token = bid / nh;
    int h = bid - token * nh;
    int pos = token & (S_LEN - 1);
    int i = threadIdx.x;
    size_t base = (size_t)token * (nh * HD) + (size_t)h * HD + 2 * i;
    float2 x = *(const float2*)(buf + base);
    float ss = x.x * x.x + x.y * x.y;
#pragma unroll
    for (int off = 32; off > 0; off >>= 1) ss += __shfl_xor(ss, off);
    float rn = 1.0f / sqrtf(ss * (1.0f / 128.0f) + 1e-6f);
    float2 wv = *(const float2*)(w + 2 * i);
    float x1 = x.x * rn * wv.x;
    float x2 = x.y * rn * wv.y;
    float c = cosT[pos * 64 + i];
    float sn = sinT[pos * 64 + i];
    float2 o;
    o.x = x1 * c - x2 * sn;
    o.y = x2 * c + x1 * sn;
    *(float2*)(buf + base) = o;
}

// ---------------------------------------------------------------------------
// In-place RMSNorm(+weight) + interleaved RoPE, bf16 buffer (q path).
// ---------------------------------------------------------------------------
__global__ __launch_bounds__(64) void norm_rope_bf16_kernel(unsigned short* __restrict__ buf,
                                                            const float* __restrict__ w,
                                                            const float* __restrict__ cosT,
                                                            const float* __restrict__ sinT,
                                                            int nh) {
    int bid = blockIdx.x;
    int token = bid / nh;
    int h = bid - token * nh;
    int pos = token & (S_LEN - 1);
    int i = threadIdx.x;
    size_t base = (size_t)token * (nh * HD) + (size_t)h * HD + 2 * i;
    unsigned int u = *(const unsigned int*)(buf + base);
    float x1 = bf_up((unsigned short)(u & 0xFFFFu));
    float x2 = bf_up((unsigned short)(u >> 16));
    float ss = x1 * x1 + x2 * x2;
#pragma unroll
    for (int off = 32; off > 0; off >>= 1) ss += __shfl_xor(ss, off);
    float rn = 1.0f / sqrtf(ss * (1.0f / 128.0f) + 1e-6f);
    float2 wv = *(const float2*)(w + 2 * i);
    x1 *= rn * wv.x;
    x2 *= rn * wv.y;
    float c = cosT[pos * 64 + i];
    float sn = sinT[pos * 64 + i];
    float o1 = x1 * c - x2 * sn;
    float o2 = x2 * c + x1 * sn;
    unsigned int ou = (unsigned int)bf_rn(o1) | ((unsigned int)bf_rn(o2) << 16);
    *(unsigned int*)(buf + base) = ou;
}

// ---------------------------------------------------------------------------
// Flash-style causal GQA attention, bf16 MFMA (16x16x32).
// Block = (64 q-rows, head h, batch b); 4 waves; wave w owns S/O row-stripe
// w*16..+15. Q bf16 [T,NH*128]; K f32 (cast in staging); V pre-transposed
// bf16 [B][KVH][128][S] (straight-copy staging). QK^T/PV use the m97
// fragment convention (k-mapping cancels); P->LDS bf16 at verified C/D
// positions. Softmax fp32, exp2 space. Output bf16.
// ---------------------------------------------------------------------------
#define PADQ 136  // Q/K LDS row stride in shorts (fragment reads: 2-way = free)
#define PADV 72   // Vt/Ps LDS row stride in shorts (fragment reads: 2-way = free)

__global__ __launch_bounds__(256) void attn_mfma_kernel(const unsigned short* __restrict__ Qb,
                                                        const float* __restrict__ Kf,
                                                        const unsigned short* __restrict__ Vb,
                                                        unsigned short* __restrict__ O) {
    __shared__ unsigned short Qs[64 * PADQ];
    __shared__ unsigned short Ks[64 * PADQ];
    __shared__ unsigned short Vt[128 * PADV];
    __shared__ unsigned short Ps[64 * PADV];
    const int t = threadIdx.x;
    const int lane = t & 63, w = t >> 6;
    const int c = lane & 15, g = lane >> 4;
    const int qt = blockIdx.x, h = blockIdx.y, b = blockIdx.z;
    const int kvh = h >> 2;  // H/KVH = 4
    const size_t tok0 = (size_t)b * S_LEN + (size_t)qt * 64;
    const size_t vbase = ((size_t)(b * NKV + kvh)) * HD * S_LEN;

    // stage Q tile (64x128 bf16, straight copy)
    {
        const int r = t >> 2, c0 = (t & 3) * 32;
        const uint4* src = (const uint4*)(Qb + (tok0 + r) * HID_D + (size_t)h * HD + c0);
        uint4* dst = (uint4*)(Qs + r * PADQ + c0);
#pragma unroll
        for (int j = 0; j < 4; ++j) dst[j] = src[j];
    }
    __syncthreads();

    // hoist Q fragments (4 k-steps over d=128)
    bf16x8 qf[4];
    {
        const unsigned short* qp = Qs + (w * 16 + c) * PADQ + g * 8;
#pragma unroll
        for (int ks = 0; ks < 4; ++ks) qf[ks] = *(const bf16x8*)(qp + ks * 32);
    }

    f32x4 o[8];
#pragma unroll
    for (int dt = 0; dt < 8; ++dt) o[dt] = (f32x4)(0.0f);
    float mrow[4], lrow[4];
#pragma unroll
    for (int r = 0; r < 4; ++r) { mrow[r] = -INFINITY; lrow[r] = 0.0f; }
    const float sc = 0.12751743f;  // log2(e)/sqrt(128)

    for (int kt = 0; kt <= qt; ++kt) {
        __syncthreads();  // previous iter's Ks/Vt reads done
        {
            // K: f32 -> bf16 cast, row-major vectorized
            const int r = t >> 2, c0 = (t & 3) * 32;
            const size_t gbase = ((size_t)b * S_LEN + (size_t)kt * 64 + r) * (NKV * HD) + (size_t)kvh * HD + c0;
            unsigned short* kd = Ks + r * PADQ + c0;
#pragma unroll
            for (int j = 0; j < 8; ++j) {
                float4 v = *(const float4*)(Kf + gbase + j * 4);
                ushort4 o4;
                o4.x = bf_rn(v.x); o4.y = bf_rn(v.y); o4.z = bf_rn(v.z); o4.w = bf_rn(v.w);
                *(ushort4*)(kd + j * 4) = o4;
            }
            // V^T: straight 16B copies from pre-transposed bf16 global
            const int vr = t >> 3;          // d-row 0..31
            const int vc8 = (t & 7) * 8;    // kv-col 0..56
            const unsigned short* vsrc = Vb + vbase + (size_t)kt * 64 + vc8;
#pragma unroll
            for (int pp = 0; pp < 4; ++pp) {
                const int d = vr + pp * 32;
                *(uint4*)(Vt + d * PADV + vc8) = *(const uint4*)(vsrc + (size_t)d * S_LEN);
            }
        }
        __syncthreads();

        // QK^T: s[ct] rows w*16+g*4+r, cols kt*64+ct*16+c
        f32x4 s[4];
#pragma unroll
        for (int ct = 0; ct < 4; ++ct) s[ct] = (f32x4)(0.0f);
#pragma unroll
        for (int ks = 0; ks < 4; ++ks) {
            bf16x8 kf[4];
#pragma unroll
            for (int ct = 0; ct < 4; ++ct)
                kf[ct] = *(const bf16x8*)(Ks + (ct * 16 + c) * PADQ + ks * 32 + g * 8);
#pragma unroll
            for (int ct = 0; ct < 4; ++ct)
                s[ct] = __builtin_amdgcn_mfma_f32_16x16x32_bf16(qf[ks], kf[ct], s[ct], 0, 0, 0);
        }

        // online softmax (exp2 space) + P -> LDS (wave-local stripe)
        const int rowbase = qt * 64 + w * 16 + g * 4;
        const int colbase = kt * 64 + c;
#pragma unroll
        for (int r = 0; r < 4; ++r) {
            float v0 = s[0][r] * sc, v1 = s[1][r] * sc, v2 = s[2][r] * sc, v3 = s[3][r] * sc;
            if (kt == qt) {
                const int rq = rowbase + r;
                if (colbase + 0  > rq) v0 = -1e30f;
                if (colbase + 16 > rq) v1 = -1e30f;
                if (colbase + 32 > rq) v2 = -1e30f;
                if (colbase + 48 > rq) v3 = -1e30f;
            }
            float mx = fmaxf(fmaxf(v0, v1), fmaxf(v2, v3));
#pragma unroll
            for (int off = 8; off > 0; off >>= 1) mx = fmaxf(mx, __shfl_xor(mx, off));
            const float mn = fmaxf(mrow[r], mx);
            const float sf = exp2f(mrow[r] - mn);
            mrow[r] = mn;
            const float p0 = exp2f(v0 - mn), p1 = exp2f(v1 - mn);
            const float p2 = exp2f(v2 - mn), p3 = exp2f(v3 - mn);
            unsigned short* pr = Ps + (w * 16 + g * 4 + r) * PADV + c;
            pr[0]  = bf_rn(p0);
            pr[16] = bf_rn(p1);
            pr[32] = bf_rn(p2);
            pr[48] = bf_rn(p3);
            float rs = p0 + p1 + p2 + p3;
#pragma unroll
            for (int off = 8; off > 0; off >>= 1) rs += __shfl_xor(rs, off);
            lrow[r] = lrow[r] * sf + rs;
#pragma unroll
            for (int dt = 0; dt < 8; ++dt) o[dt][r] *= sf;
        }
        // Ps is wave-local (wave w writes/reads only rows w*16..+15):
        // per-wave ds ordering via lgkmcnt, no barrier needed.

        // PV: o[dt] += P[stripe] x V^T[dt]
#pragma unroll
        for (int ks = 0; ks < 2; ++ks) {
            bf16x8 pf = *(const bf16x8*)(Ps + (w * 16 + c) * PADV + ks * 32 + g * 8);
#pragma unroll
            for (int dt = 0; dt < 8; ++dt) {
                bf16x8 vf = *(const bf16x8*)(Vt + (dt * 16 + c) * PADV + ks * 32 + g * 8);
                o[dt] = __builtin_amdgcn_mfma_f32_16x16x32_bf16(pf, vf, o[dt], 0, 0, 0);
            }
        }
    }

    // epilogue: /l, bf16 store (feeds Wo GEMM)
#pragma unroll
    for (int r = 0; r < 4; ++r) {
        const float inv = 1.0f / lrow[r];
        const size_t rowoff = (tok0 + w * 16 + g * 4 + r) * HID_D + (size_t)h * HD;
#pragma unroll
        for (int dt = 0; dt < 8; ++dt)
            O[rowoff + dt * 16 + c] = bf_rn(o[dt][r] * inv);
    }
}

// ---------------------------------------------------------------------------
// launch.  Workspace budget (105 MB):
//   [0]      cosT/sinT            1 MB
//   [1 MB]   qbuf  bf16 [T,4096] 32 MB  (Q proj -> norm/rope -> attn in)
//   [33 MB]  hb    bf16 [T,4096] 32 MB  (hidden bf16; reused as attn out)
//   [65 MB]  Wt    bf16 4096^2   32 MB  (Wk^T, Wv^T, Wq^T, Wo^T time-shared)
//   [97 MB]  vtb   bf16 [B][KVH][128][S] 8 MB (pre-transposed V)
// ---------------------------------------------------------------------------
extern "C" void kernel_launch(void* const* d_in, const int* in_sizes, int n_in,
                              void* d_out, int out_size, void* d_ws, size_t ws_size,
                              hipStream_t stream) {
    const int* positions = (const int*)d_in[0];
    const float* hidden  = (const float*)d_in[1];  // [T, 4096]
    const float* Wq      = (const float*)d_in[2];  // [4096, 4096]
    const float* Wk      = (const float*)d_in[3];  // [4096, 1024]
    const float* Wv      = (const float*)d_in[4];  // [4096, 1024]
    const float* Wo      = (const float*)d_in[5];  // [4096, 4096]
    const float* qw      = (const float*)d_in[6];
    const float* kw      = (const float*)d_in[7];

    float* out  = (float*)d_out;                   // [T, 4096]
    float* kout = out + (size_t)NTOK * HID_D;      // [T, 1024] f32 (k result)
    float* vout = kout + (size_t)NTOK * NKV * HD;  // [T, 1024] f32 (v result)

    char* w8 = (char*)d_ws;
    float* cosT = (float*)w8;
    float* sinT = cosT + S_LEN * 64;
    unsigned short* qbuf = (unsigned short*)(sinT + S_LEN * 64);  // 32 MB
    unsigned short* hb   = qbuf + (size_t)NTOK * HID_D;           // 32 MB
    unsigned short* Wt   = hb + (size_t)NTOK * HID_D;             // 32 MB (time-shared)
    unsigned short* vtb  = Wt + (size_t)HID_D * HID_D;            //  8 MB
    unsigned short* ab   = hb;  // attn output reuses hidden-bf16 region

    rope_table_kernel<<<S_LEN, 64, 0, stream>>>(positions, cosT, sinT);
    castv_kernel<<<(NTOK * HID_D / 4 + 255) / 256, 256, 0, stream>>>(hidden, hb, NTOK * HID_D / 4);

    // K projection (f32 -> d_out k section)
    cast_t_kernel<<<dim3(NKV * HD / 32, HID_D / 32), 256, 0, stream>>>(Wk, Wt, HID_D, NKV * HD);
    gemm_bt_kernel<float><<<dim3(NKV * HD / 128, NTOK / 128), 256, 0, stream>>>(hb, Wt, kout, NTOK, NKV * HD, HID_D);
    // V projection (f32 -> d_out v section), then global V transpose to bf16
    cast_t_kernel<<<dim3(NKV * HD / 32, HID_D / 32), 256, 0, stream>>>(Wv, Wt, HID_D, NKV * HD);
    gemm_bt_kernel<float><<<dim3(NKV * HD / 128, NTOK / 128), 256, 0, stream>>>(hb, Wt, vout, NTOK, NKV * HD, HID_D);
    vtrans_kernel<<<dim3(S_LEN / 32, HD / 32, B_SZ * NKV), 256, 0, stream>>>(vout, vtb);
    // Q projection (bf16 -> qbuf)
    cast_t_kernel<<<dim3(HID_D / 32, HID_D / 32), 256, 0, stream>>>(Wq, Wt, HID_D, HID_D);
    gemm_bt_kernel<unsigned short><<<dim3(HID_D / 128, NTOK / 128), 256, 0, stream>>>(hb, Wt, qbuf, NTOK, HID_D, HID_D);
    // Wo transpose (Wt region free after Q GEMM)
    cast_t_kernel<<<dim3(HID_D / 32, HID_D / 32), 256, 0, stream>>>(Wo, Wt, HID_D, HID_D);

    // RMSNorm + RoPE (q on bf16 in ws; k on f32 in d_out)
    norm_rope_bf16_kernel<<<NTOK * NH, 64, 0, stream>>>(qbuf, qw, cosT, sinT, NH);
    norm_rope_kernel<<<NTOK * NKV, 64, 0, stream>>>(kout, kw, cosT, sinT, NKV);

    // attention: q bf16, k f32, v pre-transposed bf16 -> bf16 attn-out in ab
    attn_mfma_kernel<<<dim3(S_LEN / 64, NH, B_SZ), 256, 0, stream>>>(qbuf, kout, vtb, ab);

    // output projection
    gemm_bt_kernel<float><<<dim3(HID_D / 128, NTOK / 128), 256, 0, stream>>>(ab, Wt, out, NTOK, HID_D, HID_D);
}